// Round 2
// 806.868 us; speedup vs baseline: 1.0907x; 1.0907x over previous
//
#include <hip/hip_runtime.h>
#include <hip/hip_bf16.h>

typedef __hip_bfloat16 bf16;
typedef __bf16 bf16x8 __attribute__((ext_vector_type(8)));
typedef float f32x4 __attribute__((ext_vector_type(4)));

#define NU 40000
#define NI 60000
#define NN 100000
#define DF 1024
#define DL 128
#define DI 64
#define NE 1600000
#define CAP 64

__device__ __forceinline__ float leaky(float v) { return v > 0.0f ? v : 0.01f * v; }

// f32 -> bf16 round-to-nearest-even
__device__ __forceinline__ unsigned short f2b(float f) {
    unsigned u = __builtin_bit_cast(unsigned, f);
    unsigned r = (u + 0x7FFFu + ((u >> 16) & 1u)) >> 16;
    return (unsigned short)r;
}
__device__ __forceinline__ bf16 tobf(float f) {
    unsigned short r = f2b(f);
    return __builtin_bit_cast(bf16, r);
}
__device__ __forceinline__ unsigned pk2(float x, float y) {
    return (unsigned)f2b(x) | ((unsigned)f2b(y) << 16);
}
__device__ __forceinline__ float b2f_lo(unsigned u) { return __builtin_bit_cast(float, u << 16); }
__device__ __forceinline__ float b2f_hi(unsigned u) { return __builtin_bit_cast(float, u & 0xffff0000u); }

// stage 8 consecutive elements into LDS (T=bf16: raw copy; T=float: convert)
template<typename T>
__device__ __forceinline__ void stage8(bf16* dst, const T* src) {
    if constexpr (sizeof(T) == 2) {
        *(uint4*)dst = *(const uint4*)src;
    } else {
        float4 a = *(const float4*)src;
        float4 b = *(const float4*)(src + 4);
        uint2 lo, hi;
        lo.x = pk2(a.x, a.y); lo.y = pk2(a.z, a.w);
        hi.x = pk2(b.x, b.y); hi.y = pk2(b.z, b.w);
        *(uint2*)dst = lo;
        *(uint2*)(dst + 4) = hi;
    }
}
__device__ __forceinline__ void zero8(bf16* dst) {
    uint4 z = {0u, 0u, 0u, 0u};
    *(uint4*)dst = z;
}

// ---------------- CSR (bucket) build ----------------
__global__ void csr_fill(const int* __restrict__ ei, int* __restrict__ cnt,
                         int* __restrict__ bucket) {
    int e = blockIdx.x * 256 + threadIdx.x;
    if (e >= NE) return;
    int s = ei[e];          // src
    int d = ei[NE + e];     // dst
    int p = atomicAdd(&cnt[d], 1);
    if (p < CAP) bucket[d * CAP + p] = s;
}

// ---------------- weight transpose+convert ([K,M] f32 -> [M,K] bf16) ----------------
template<int K, int M>
__global__ void transpose_kernel(const float* __restrict__ W, bf16* __restrict__ Wt) {
    int idx = blockIdx.x * 256 + threadIdx.x;
    if (idx < K * M) {
        int k = idx / M, m = idx % M;
        Wt[m * K + k] = tobf(W[k * M + m]);
    }
}

// ---------------- plain f32 -> bf16 convert, 4 elems/thread ----------------
__global__ void convert_kernel(const float* __restrict__ W, bf16* __restrict__ out) {
    int i = blockIdx.x * 256 + threadIdx.x;
    float4 v = *(const float4*)(W + (size_t)i * 4);
    uint2 p;
    p.x = pk2(v.x, v.y);
    p.y = pk2(v.z, v.w);
    *(uint2*)(out + (size_t)i * 4) = p;
}

// ---------------- GEMM1: temp[NI,DL] = features[NI,DF] @ mlp_w[DL,DF]^T + mlp_b ----
// BM=64 rows/block (938 blocks), double-buffered LDS, reg-staged prefetch (T14),
// XOR-swizzled tiles (chunk ^= row&7) to kill the 16-way ds_read bank conflict.
// Wave layout 2M x 2N: each wave computes 32 rows x 64 cols.
__global__ __launch_bounds__(256) void gemm1_kernel(const float* __restrict__ A,
                                                    const bf16* __restrict__ Wb,
                                                    const float* __restrict__ bias,
                                                    bf16* __restrict__ out) {
    __shared__ __align__(16) bf16 As[2][64 * 64];
    __shared__ __align__(16) bf16 Bs[2][128 * 64];
    int t = threadIdx.x;
    int wave = t >> 6, lane = t & 63, q = lane >> 4, l16 = lane & 15;
    int wm = wave >> 1, wn = wave & 1;
    int row0 = blockIdx.x * 64;

    const float* ap[2];
    const bf16* bp[4];
    int aoff[2], boff[4];
    bool aval[2];
    #pragma unroll
    for (int i = 0; i < 2; i++) {
        int slot = t + i * 256;
        int r = slot >> 3, kc = (slot & 7) * 8;
        ap[i] = A + (size_t)(row0 + r) * DF + kc;
        aval[i] = (row0 + r) < NI;
        aoff[i] = r * 64 + (((kc >> 3) ^ (r & 7)) << 3);
    }
    #pragma unroll
    for (int i = 0; i < 4; i++) {
        int slot = t + i * 256;
        int r = slot >> 3, kc = (slot & 7) * 8;
        bp[i] = Wb + (size_t)r * DF + kc;
        boff[i] = r * 64 + (((kc >> 3) ^ (r & 7)) << 3);
    }

    float4 av[2][2];
    uint4 bv[4];
    auto issue = [&](int k0) {
        #pragma unroll
        for (int i = 0; i < 2; i++) {
            if (aval[i]) {
                av[i][0] = *(const float4*)(ap[i] + k0);
                av[i][1] = *(const float4*)(ap[i] + k0 + 4);
            } else {
                av[i][0] = float4{0.f, 0.f, 0.f, 0.f};
                av[i][1] = float4{0.f, 0.f, 0.f, 0.f};
            }
        }
        #pragma unroll
        for (int i = 0; i < 4; i++) bv[i] = *(const uint4*)(bp[i] + k0);
    };
    auto commit = [&](int buf) {
        #pragma unroll
        for (int i = 0; i < 2; i++) {
            uint4 pkd;
            pkd.x = pk2(av[i][0].x, av[i][0].y);
            pkd.y = pk2(av[i][0].z, av[i][0].w);
            pkd.z = pk2(av[i][1].x, av[i][1].y);
            pkd.w = pk2(av[i][1].z, av[i][1].w);
            *(uint4*)(&As[buf][aoff[i]]) = pkd;
        }
        #pragma unroll
        for (int i = 0; i < 4; i++) *(uint4*)(&Bs[buf][boff[i]]) = bv[i];
    };

    f32x4 acc[2][4] = {};
    issue(0);
    commit(0);
    __syncthreads();
    for (int k0i = 0; k0i < 16; k0i++) {
        int buf = k0i & 1;
        if (k0i < 15) issue((k0i + 1) * 64);   // prefetch next K-tile into regs
        #pragma unroll
        for (int kk = 0; kk < 64; kk += 32) {
            int ch = (kk >> 3) + q;
            int ra = wm * 32 + l16;
            bf16x8 a0 = *(const bf16x8*)&As[buf][ra * 64 + ((ch ^ (ra & 7)) << 3)];
            bf16x8 a1 = *(const bf16x8*)&As[buf][(ra + 16) * 64 + ((ch ^ (ra & 7)) << 3)];
            #pragma unroll
            for (int nt = 0; nt < 4; nt++) {
                int rb = wn * 64 + nt * 16 + l16;
                bf16x8 b = *(const bf16x8*)&Bs[buf][rb * 64 + ((ch ^ (rb & 7)) << 3)];
                acc[0][nt] = __builtin_amdgcn_mfma_f32_16x16x32_bf16(a0, b, acc[0][nt], 0, 0, 0);
                acc[1][nt] = __builtin_amdgcn_mfma_f32_16x16x32_bf16(a1, b, acc[1][nt], 0, 0, 0);
            }
        }
        if (k0i < 15) {
            commit(buf ^ 1);     // write prefetched tile into the other buffer
            __syncthreads();     // single barrier per K-step
        }
    }
    #pragma unroll
    for (int mt = 0; mt < 2; mt++) {
        #pragma unroll
        for (int nt = 0; nt < 4; nt++) {
            int col = wn * 64 + nt * 16 + l16;
            float bvv = bias[col];
            #pragma unroll
            for (int r = 0; r < 4; r++) {
                int row = row0 + wm * 32 + mt * 16 + q * 4 + r;
                if (row < NI) out[(size_t)row * DL + col] = tobf(acc[mt][nt][r] + bvv);
            }
        }
    }
}

// ---------------- normalize + concat -> x0[NN,DL] ----------------
__global__ __launch_bounds__(256) void norm_kernel(const float* __restrict__ pref,
                                                   const bf16* __restrict__ temp,
                                                   bf16* __restrict__ x0) {
    __shared__ float wsum[4];
    int t = threadIdx.x;
    int g = t >> 7;            // 2 rows per 256-thread block
    int c = t & 127;
    int row = blockIdx.x * 2 + g;
    float v = (row < NU) ? pref[(size_t)row * DL + c]
                         : (float)temp[(size_t)(row - NU) * DL + c];
    float ss = v * v;
    #pragma unroll
    for (int off = 32; off > 0; off >>= 1) ss += __shfl_down(ss, off);
    int wave = t >> 6;
    if ((t & 63) == 0) wsum[wave] = ss;
    __syncthreads();
    float tot = wsum[g * 2] + wsum[g * 2 + 1];
    float inv = 1.0f / fmaxf(sqrtf(tot), 1e-12f);
    x0[(size_t)row * DL + c] = tobf(v * inv);
}

// ---------------- generic small GEMM with fused epilogue ----------------
// C[nrows,M] = A[nrows,K](bf16) @ Wt[M,K](WT)^T
// EPI 0: out = z                               (OutT=bf16)
// EPI 1: out = leaky(z + bias) + extra         (extra f32 id_emb, OutT=float)
// EPI 2: out = leaky(z + bias + extra)         (extra f32 xhat,   OutT=bf16|float)
template<typename WT, int K, int M, int EPI, typename OutT>
__global__ __launch_bounds__(256) void sgemm_kernel(const bf16* __restrict__ A,
                                                    const WT* __restrict__ Wt,
                                                    const float* __restrict__ bias,
                                                    const float* __restrict__ extra,
                                                    OutT* __restrict__ out,
                                                    int nrows) {
    __shared__ __align__(16) bf16 As[128 * K];
    __shared__ __align__(16) bf16 Ws[M * K];
    int t = threadIdx.x;
    int wave = t >> 6, lane = t & 63;
    int q = lane >> 4, l16 = lane & 15;
    int row0 = blockIdx.x * 128;
    constexpr int WSLOT = M * K / 8;
    for (int slot = t; slot < WSLOT; slot += 256)
        stage8(Ws + slot * 8, Wt + (size_t)slot * 8);
    constexpr int SLOTS = 128 * K / 8;
    for (int slot = t; slot < SLOTS; slot += 256) {
        int r = slot / (K / 8);
        int kc = (slot % (K / 8)) * 8;
        int gr = row0 + r;
        if (gr < nrows) *(uint4*)(As + r * K + kc) = *(const uint4*)(A + (size_t)gr * K + kc);
        else            zero8(As + r * K + kc);
    }
    __syncthreads();
    constexpr int NT = M / 16;
    f32x4 acc[2][NT] = {};
    #pragma unroll
    for (int kk = 0; kk < K; kk += 32) {
        bf16x8 a0 = *(const bf16x8*)(As + (wave * 32 + l16) * K + kk + q * 8);
        bf16x8 a1 = *(const bf16x8*)(As + (wave * 32 + 16 + l16) * K + kk + q * 8);
        #pragma unroll
        for (int nt = 0; nt < NT; nt++) {
            bf16x8 b = *(const bf16x8*)(Ws + (nt * 16 + l16) * K + kk + q * 8);
            acc[0][nt] = __builtin_amdgcn_mfma_f32_16x16x32_bf16(a0, b, acc[0][nt], 0, 0, 0);
            acc[1][nt] = __builtin_amdgcn_mfma_f32_16x16x32_bf16(a1, b, acc[1][nt], 0, 0, 0);
        }
    }
    #pragma unroll
    for (int mt = 0; mt < 2; mt++) {
        #pragma unroll
        for (int nt = 0; nt < NT; nt++) {
            int col = nt * 16 + l16;
            float bv = (EPI != 0) ? bias[col] : 0.0f;
            #pragma unroll
            for (int r = 0; r < 4; r++) {
                int row = row0 + wave * 32 + mt * 16 + q * 4 + r;
                if (row < nrows) {
                    float z = acc[mt][nt][r];
                    if (EPI == 1) {
                        z = leaky(z + bv) + extra[(size_t)row * M + col];
                    } else if (EPI == 2) {
                        z = leaky(z + bv + extra[(size_t)row * M + col]);
                    }
                    if constexpr (sizeof(OutT) == 2) out[(size_t)row * M + col] = tobf(z);
                    else                             out[(size_t)row * M + col] = z;
                }
            }
        }
    }
}

// ---------------- gather + leaky: h[d,:] = leaky(sum over in-edges of xw[src,:]) ----
// uint2 loads: 4 bf16 cols/thread, D/4 threads per node.
template<int D>
__global__ __launch_bounds__(256) void gather_kernel(const bf16* __restrict__ xw,
                                                     const int* __restrict__ cnt,
                                                     const int* __restrict__ bucket,
                                                     bf16* __restrict__ h) {
    constexpr int TPN = D / 4;          // threads per node
    constexpr int GP = 256 / TPN;       // nodes per block
    __shared__ int srcs[GP][CAP];
    int g = threadIdx.x / TPN;
    int c = threadIdx.x % TPN;          // uint2 (4-col) index
    int node = blockIdx.x * GP + g;
    int deg = min(cnt[node], CAP);
    for (int i = c; i < deg; i += TPN) srcs[g][i] = bucket[node * CAP + i];
    __syncthreads();
    const uint2* x2 = (const uint2*)xw;
    float s0 = 0.0f, s1 = 0.0f, s2 = 0.0f, s3 = 0.0f;
    for (int i = 0; i < deg; i++) {
        int s = srcs[g][i];
        uint2 v = x2[(size_t)s * (D / 4) + c];
        s0 += b2f_lo(v.x); s1 += b2f_hi(v.x);
        s2 += b2f_lo(v.y); s3 += b2f_hi(v.y);
    }
    uint2 o;
    o.x = pk2(leaky(s0), leaky(s1));
    o.y = pk2(leaky(s2), leaky(s3));
    *(uint2*)(h + (size_t)node * D + c * 4) = o;
}

extern "C" void kernel_launch(void* const* d_in, const int* in_sizes, int n_in,
                              void* d_out, int out_size, void* d_ws, size_t ws_size,
                              hipStream_t stream) {
    // Robust input mapping by element count (canonical setup_inputs order as fallback).
    const void* p[16];
    for (int i = 0; i < 16 && i < n_in; i++) p[i] = d_in[i];
    if (n_in == 16) {
        int n8192 = 0, n4096 = 0, n64 = 0;
        const int idx64[4] = {7, 9, 12, 14};
        const int idx4096[3] = {10, 11, 13};
        for (int i = 0; i < 16; i++) {
            switch (in_sizes[i]) {
                case 61440000: p[0] = d_in[i]; break;                  // features
                case 6400000:  p[1] = d_in[i]; break;                  // id_embedding
                case 5120000:  p[2] = d_in[i]; break;                  // preference
                case 131072:   p[3] = d_in[i]; break;                  // mlp_w
                case 128:      p[4] = d_in[i]; break;                  // mlp_b
                case 16384:    p[5] = d_in[i]; break;                  // conv1_w
                case 8192:     p[n8192++ ? 8 : 6] = d_in[i]; break;    // lin1_w, g1_w
                case 64:       if (n64 < 4) p[idx64[n64++]] = d_in[i]; break;
                case 4096:     if (n4096 < 3) p[idx4096[n4096++]] = d_in[i]; break;
                case 3200000:  p[15] = d_in[i]; break;                 // edge_index
                default: break;
            }
        }
    }
    const float* features = (const float*)p[0];
    const float* id_emb   = (const float*)p[1];
    const float* pref     = (const float*)p[2];
    const float* mlp_w    = (const float*)p[3];
    const float* mlp_b    = (const float*)p[4];
    const float* conv1_w  = (const float*)p[5];
    const float* lin1_w   = (const float*)p[6];
    const float* lin1_b   = (const float*)p[7];
    const float* g1_w     = (const float*)p[8];
    const float* g1_b     = (const float*)p[9];
    const float* conv2_w  = (const float*)p[10];
    const float* lin2_w   = (const float*)p[11];
    const float* lin2_b   = (const float*)p[12];
    const float* g2_w     = (const float*)p[13];
    const float* g2_b     = (const float*)p[14];
    const int*   ei       = (const int*)p[15];

    char* wsp = (char*)d_ws;
    size_t off = 0;
    auto alloc = [&](size_t bytes) {
        void* ptr = wsp + off;
        off += (bytes + 255) & ~(size_t)255;
        return ptr;
    };
    // regions (sequential lifetimes), ~103 MB total (same footprint as passing version):
    //   A: temp[NI,128]bf16 -> h1[NN,128]bf16 -> h2[NN,64]bf16
    //   B: x0[NN,128]bf16   -> xw2[NN,64]bf16
    //   C: mwb[DL,DF]bf16 (gemm1 only) -> xw1[NN,128]bf16 -> xhat[NN,64]f32
    //   x1[NN,64]bf16 lives in d_out's first half (dead before final f32 write)
    void* regA = alloc((size_t)NN * DL * 2);
    void* regB = alloc((size_t)NN * DL * 2);
    void* regC = alloc((size_t)NN * DL * 2);
    int*  cnt    = (int*) alloc((size_t)NN * 4);
    int*  bucket = (int*) alloc((size_t)NN * CAP * 4);
    bf16* c1t    = (bf16*)alloc((size_t)DL * DL * 2);
    bf16* c2t    = (bf16*)alloc((size_t)DI * DI * 2);

    bf16*  temp = (bf16*)regA;
    bf16*  h1   = (bf16*)regA;
    bf16*  h2   = (bf16*)regA;
    bf16*  x0   = (bf16*)regB;
    bf16*  xw2  = (bf16*)regB;
    bf16*  mwb  = (bf16*)regC;        // mlp_w bf16 copy, dead after gemm1
    bf16*  xw1  = (bf16*)regC;
    float* xhat = (float*)regC;
    bf16*  x1   = (bf16*)d_out;       // scratch in output buffer (f32-sized)
    float* out  = (float*)d_out;      // final output: float32

    hipMemsetAsync(cnt, 0, (size_t)NN * 4, stream);
    csr_fill<<<NE / 256, 256, 0, stream>>>(ei, cnt, bucket);

    transpose_kernel<DL, DL><<<(DL * DL + 255) / 256, 256, 0, stream>>>(conv1_w, c1t);
    transpose_kernel<DI, DI><<<(DI * DI + 255) / 256, 256, 0, stream>>>(conv2_w, c2t);
    convert_kernel<<<(DL * DF) / 1024, 256, 0, stream>>>(mlp_w, mwb);

    gemm1_kernel<<<(NI + 63) / 64, 256, 0, stream>>>(features, mwb, mlp_b, temp);
    norm_kernel<<<NN / 2, 256, 0, stream>>>(pref, temp, x0);

    const int SG = (NN + 127) / 128;
    // ----- layer 1 -----
    sgemm_kernel<bf16, DL, DL, 0, bf16><<<SG, 256, 0, stream>>>(x0, c1t, nullptr, nullptr, xw1, NN);
    gather_kernel<DL><<<NN / 8, 256, 0, stream>>>(xw1, cnt, bucket, h1);
    sgemm_kernel<float, DL, DI, 1, float><<<SG, 256, 0, stream>>>(x0, lin1_w, lin1_b, id_emb, xhat, NN);
    sgemm_kernel<float, DL, DI, 2, bf16><<<SG, 256, 0, stream>>>(h1, g1_w, g1_b, xhat, x1, NN);
    // ----- layer 2 -----
    sgemm_kernel<float, DI, DI, 1, float><<<SG, 256, 0, stream>>>(x1, lin2_w, lin2_b, id_emb, xhat, NN);
    sgemm_kernel<bf16, DI, DI, 0, bf16><<<SG, 256, 0, stream>>>(x1, c2t, nullptr, nullptr, xw2, NN);
    gather_kernel<DI><<<NN / 16, 256, 0, stream>>>(xw2, cnt, bucket, h2);
    sgemm_kernel<float, DI, DI, 2, float><<<SG, 256, 0, stream>>>(h2, g2_w, g2_b, xhat, out, NN);
}

// Round 3
// 780.123 us; speedup vs baseline: 1.1281x; 1.0343x over previous
//
#include <hip/hip_runtime.h>
#include <hip/hip_bf16.h>

typedef __hip_bfloat16 bf16;
typedef __bf16 bf16x8 __attribute__((ext_vector_type(8)));
typedef float f32x4 __attribute__((ext_vector_type(4)));

#define NU 40000
#define NI 60000
#define NN 100000
#define DF 1024
#define DL 128
#define DI 64
#define NE 1600000
#define CAP 64

__device__ __forceinline__ float leaky(float v) { return v > 0.0f ? v : 0.01f * v; }

// f32 -> bf16 round-to-nearest-even
__device__ __forceinline__ unsigned short f2b(float f) {
    unsigned u = __builtin_bit_cast(unsigned, f);
    unsigned r = (u + 0x7FFFu + ((u >> 16) & 1u)) >> 16;
    return (unsigned short)r;
}
__device__ __forceinline__ bf16 tobf(float f) {
    unsigned short r = f2b(f);
    return __builtin_bit_cast(bf16, r);
}
__device__ __forceinline__ unsigned pk2(float x, float y) {
    return (unsigned)f2b(x) | ((unsigned)f2b(y) << 16);
}
__device__ __forceinline__ float b2f_lo(unsigned u) { return __builtin_bit_cast(float, u << 16); }
__device__ __forceinline__ float b2f_hi(unsigned u) { return __builtin_bit_cast(float, u & 0xffff0000u); }

// ---------------- CSR (bucket) build ----------------
__global__ void csr_fill(const int* __restrict__ ei, int* __restrict__ cnt,
                         int* __restrict__ bucket) {
    int e = blockIdx.x * 256 + threadIdx.x;
    if (e >= NE) return;
    int s = ei[e];          // src
    int d = ei[NE + e];     // dst
    int p = atomicAdd(&cnt[d], 1);
    if (p < CAP) bucket[d * CAP + p] = s;
}

// ---------------- one-shot weight prep: converts + transposes, single launch ----
// blocks 0..127   : mwb  = bf16(mlp_w)           131072 elems (float4/thread)
// blocks 128..191 : c1t  = bf16(conv1_w^T)       128x128
// blocks 192..207 : c2t  = bf16(conv2_w^T)       64x64
// blocks 208..239 : l1b  = bf16(lin1_w)          [64,128] already [M,K]
// blocks 240..271 : g1b  = bf16(g1_w)
// blocks 272..287 : l2b  = bf16(lin2_w)          [64,64]
// blocks 288..303 : g2b  = bf16(g2_w)
__global__ __launch_bounds__(256) void prep_kernel(
        const float* __restrict__ mlp_w, const float* __restrict__ conv1_w,
        const float* __restrict__ conv2_w, const float* __restrict__ lin1_w,
        const float* __restrict__ g1_w, const float* __restrict__ lin2_w,
        const float* __restrict__ g2_w,
        bf16* __restrict__ mwb, bf16* __restrict__ c1t, bf16* __restrict__ c2t,
        bf16* __restrict__ l1b, bf16* __restrict__ g1b,
        bf16* __restrict__ l2b, bf16* __restrict__ g2b) {
    int b = blockIdx.x, t = threadIdx.x;
    if (b < 128) {
        int i = b * 256 + t;
        float4 v = *(const float4*)(mlp_w + (size_t)i * 4);
        uint2 pk;
        pk.x = pk2(v.x, v.y);
        pk.y = pk2(v.z, v.w);
        *(uint2*)(mwb + (size_t)i * 4) = pk;
    } else if (b < 192) {
        int i = (b - 128) * 256 + t;      // i = k*128+m
        int k = i >> 7, m = i & 127;
        c1t[m * 128 + k] = tobf(conv1_w[i]);
    } else if (b < 208) {
        int i = (b - 192) * 256 + t;      // i = k*64+m
        int k = i >> 6, m = i & 63;
        c2t[m * 64 + k] = tobf(conv2_w[i]);
    } else if (b < 240) {
        int i = (b - 208) * 256 + t;
        l1b[i] = tobf(lin1_w[i]);
    } else if (b < 272) {
        int i = (b - 240) * 256 + t;
        g1b[i] = tobf(g1_w[i]);
    } else if (b < 288) {
        int i = (b - 272) * 256 + t;
        l2b[i] = tobf(lin2_w[i]);
    } else {
        int i = (b - 288) * 256 + t;
        g2b[i] = tobf(g2_w[i]);
    }
}

// ---------------- GEMM1: temp[NI,DL] = features[NI,DF] @ mlp_w[DL,DF]^T + mlp_b ----
// BM=64 rows/block (938 blocks), double-buffered LDS, reg-staged prefetch (T14),
// XOR-swizzled tiles (chunk ^= row&7). Wave layout 2M x 2N.  (unchanged - verified)
__global__ __launch_bounds__(256) void gemm1_kernel(const float* __restrict__ A,
                                                    const bf16* __restrict__ Wb,
                                                    const float* __restrict__ bias,
                                                    bf16* __restrict__ out) {
    __shared__ __align__(16) bf16 As[2][64 * 64];
    __shared__ __align__(16) bf16 Bs[2][128 * 64];
    int t = threadIdx.x;
    int wave = t >> 6, lane = t & 63, q = lane >> 4, l16 = lane & 15;
    int wm = wave >> 1, wn = wave & 1;
    int row0 = blockIdx.x * 64;

    const float* ap[2];
    const bf16* bp[4];
    int aoff[2], boff[4];
    bool aval[2];
    #pragma unroll
    for (int i = 0; i < 2; i++) {
        int slot = t + i * 256;
        int r = slot >> 3, kc = (slot & 7) * 8;
        ap[i] = A + (size_t)(row0 + r) * DF + kc;
        aval[i] = (row0 + r) < NI;
        aoff[i] = r * 64 + (((kc >> 3) ^ (r & 7)) << 3);
    }
    #pragma unroll
    for (int i = 0; i < 4; i++) {
        int slot = t + i * 256;
        int r = slot >> 3, kc = (slot & 7) * 8;
        bp[i] = Wb + (size_t)r * DF + kc;
        boff[i] = r * 64 + (((kc >> 3) ^ (r & 7)) << 3);
    }

    float4 av[2][2];
    uint4 bv[4];
    auto issue = [&](int k0) {
        #pragma unroll
        for (int i = 0; i < 2; i++) {
            if (aval[i]) {
                av[i][0] = *(const float4*)(ap[i] + k0);
                av[i][1] = *(const float4*)(ap[i] + k0 + 4);
            } else {
                av[i][0] = float4{0.f, 0.f, 0.f, 0.f};
                av[i][1] = float4{0.f, 0.f, 0.f, 0.f};
            }
        }
        #pragma unroll
        for (int i = 0; i < 4; i++) bv[i] = *(const uint4*)(bp[i] + k0);
    };
    auto commit = [&](int buf) {
        #pragma unroll
        for (int i = 0; i < 2; i++) {
            uint4 pkd;
            pkd.x = pk2(av[i][0].x, av[i][0].y);
            pkd.y = pk2(av[i][0].z, av[i][0].w);
            pkd.z = pk2(av[i][1].x, av[i][1].y);
            pkd.w = pk2(av[i][1].z, av[i][1].w);
            *(uint4*)(&As[buf][aoff[i]]) = pkd;
        }
        #pragma unroll
        for (int i = 0; i < 4; i++) *(uint4*)(&Bs[buf][boff[i]]) = bv[i];
    };

    f32x4 acc[2][4] = {};
    issue(0);
    commit(0);
    __syncthreads();
    for (int k0i = 0; k0i < 16; k0i++) {
        int buf = k0i & 1;
        if (k0i < 15) issue((k0i + 1) * 64);
        #pragma unroll
        for (int kk = 0; kk < 64; kk += 32) {
            int ch = (kk >> 3) + q;
            int ra = wm * 32 + l16;
            bf16x8 a0 = *(const bf16x8*)&As[buf][ra * 64 + ((ch ^ (ra & 7)) << 3)];
            bf16x8 a1 = *(const bf16x8*)&As[buf][(ra + 16) * 64 + ((ch ^ (ra & 7)) << 3)];
            #pragma unroll
            for (int nt = 0; nt < 4; nt++) {
                int rb = wn * 64 + nt * 16 + l16;
                bf16x8 b = *(const bf16x8*)&Bs[buf][rb * 64 + ((ch ^ (rb & 7)) << 3)];
                acc[0][nt] = __builtin_amdgcn_mfma_f32_16x16x32_bf16(a0, b, acc[0][nt], 0, 0, 0);
                acc[1][nt] = __builtin_amdgcn_mfma_f32_16x16x32_bf16(a1, b, acc[1][nt], 0, 0, 0);
            }
        }
        if (k0i < 15) {
            commit(buf ^ 1);
            __syncthreads();
        }
    }
    #pragma unroll
    for (int mt = 0; mt < 2; mt++) {
        #pragma unroll
        for (int nt = 0; nt < 4; nt++) {
            int col = wn * 64 + nt * 16 + l16;
            float bvv = bias[col];
            #pragma unroll
            for (int r = 0; r < 4; r++) {
                int row = row0 + wm * 32 + mt * 16 + q * 4 + r;
                if (row < NI) out[(size_t)row * DL + col] = tobf(acc[mt][nt][r] + bvv);
            }
        }
    }
}

// ---------------- normalize + concat -> x0[NN,DL] ----------------
__global__ __launch_bounds__(256) void norm_kernel(const float* __restrict__ pref,
                                                   const bf16* __restrict__ temp,
                                                   bf16* __restrict__ x0) {
    __shared__ float wsum[4];
    int t = threadIdx.x;
    int g = t >> 7;            // 2 rows per 256-thread block
    int c = t & 127;
    int row = blockIdx.x * 2 + g;
    float v = (row < NU) ? pref[(size_t)row * DL + c]
                         : (float)temp[(size_t)(row - NU) * DL + c];
    float ss = v * v;
    #pragma unroll
    for (int off = 32; off > 0; off >>= 1) ss += __shfl_down(ss, off);
    int wave = t >> 6;
    if ((t & 63) == 0) wsum[wave] = ss;
    __syncthreads();
    float tot = wsum[g * 2] + wsum[g * 2 + 1];
    float inv = 1.0f / fmaxf(sqrtf(tot), 1e-12f);
    x0[(size_t)row * DL + c] = tobf(v * inv);
}

// ---------------- no-LDS fused GEMM: up to two weight matrices, one A read ------
// C1[nrows,M1] = A[nrows,K] @ W1[M1,K]^T  (+ optional C2 with W2)
// EPI 0: out = z (bf16)
// EPI 1: out = leaky(z + bias) + extra    (f32 out)
// EPI 2: out = leaky(z + bias + extra)
// A fragments loaded straight from global (each element consumed by exactly one
// wave, reused across all N-tiles in registers); W fragments from L1/L2.
// Zero LDS, zero barriers -> latency hidden by occupancy.
template<int K, int M1, int EPI1, typename Out1T, int M2, int EPI2, typename Out2T>
__global__ __launch_bounds__(256) void fgemm_kernel(
        const bf16* __restrict__ A,
        const bf16* __restrict__ W1, const float* __restrict__ b1,
        const float* __restrict__ e1, Out1T* __restrict__ o1,
        const bf16* __restrict__ W2, const float* __restrict__ b2,
        const float* __restrict__ e2, Out2T* __restrict__ o2,
        int nrows) {
    constexpr int NT1 = M1 / 16;
    constexpr int NT2 = (M2 > 0) ? (M2 / 16) : 0;
    int t = threadIdx.x;
    int wave = t >> 6, lane = t & 63, q = lane >> 4, l16 = lane & 15;
    int rbase = blockIdx.x * 128 + wave * 32;
    int r0 = rbase + l16, r1 = r0 + 16;
    const bf16* a0p = A + (size_t)r0 * K + q * 8;
    const bf16* a1p = A + (size_t)r1 * K + q * 8;
    bool v0 = r0 < nrows, v1 = r1 < nrows;
    f32x4 acc1[2][NT1] = {};
    f32x4 acc2[2][NT2 ? NT2 : 1] = {};
    const bf16x8 zz = {};
    #pragma unroll
    for (int kk = 0; kk < K; kk += 32) {
        bf16x8 a0 = v0 ? *(const bf16x8*)(a0p + kk) : zz;
        bf16x8 a1 = v1 ? *(const bf16x8*)(a1p + kk) : zz;
        #pragma unroll
        for (int nt = 0; nt < NT1; nt++) {
            bf16x8 b = *(const bf16x8*)(W1 + (size_t)(nt * 16 + l16) * K + kk + q * 8);
            acc1[0][nt] = __builtin_amdgcn_mfma_f32_16x16x32_bf16(a0, b, acc1[0][nt], 0, 0, 0);
            acc1[1][nt] = __builtin_amdgcn_mfma_f32_16x16x32_bf16(a1, b, acc1[1][nt], 0, 0, 0);
        }
        if constexpr (NT2 > 0) {
            #pragma unroll
            for (int nt = 0; nt < NT2; nt++) {
                bf16x8 b = *(const bf16x8*)(W2 + (size_t)(nt * 16 + l16) * K + kk + q * 8);
                acc2[0][nt] = __builtin_amdgcn_mfma_f32_16x16x32_bf16(a0, b, acc2[0][nt], 0, 0, 0);
                acc2[1][nt] = __builtin_amdgcn_mfma_f32_16x16x32_bf16(a1, b, acc2[1][nt], 0, 0, 0);
            }
        }
    }
    #pragma unroll
    for (int mt = 0; mt < 2; mt++) {
        #pragma unroll
        for (int nt = 0; nt < NT1; nt++) {
            int col = nt * 16 + l16;
            float bv = (EPI1 != 0) ? b1[col] : 0.0f;
            #pragma unroll
            for (int r = 0; r < 4; r++) {
                int row = rbase + mt * 16 + q * 4 + r;
                if (row < nrows) {
                    float z = acc1[mt][nt][r];
                    if constexpr (EPI1 == 1) z = leaky(z + bv) + e1[(size_t)row * M1 + col];
                    else if constexpr (EPI1 == 2) z = leaky(z + bv + e1[(size_t)row * M1 + col]);
                    if constexpr (sizeof(Out1T) == 2) o1[(size_t)row * M1 + col] = tobf(z);
                    else                              o1[(size_t)row * M1 + col] = z;
                }
            }
        }
    }
    if constexpr (NT2 > 0) {
        #pragma unroll
        for (int mt = 0; mt < 2; mt++) {
            #pragma unroll
            for (int nt = 0; nt < NT2; nt++) {
                int col = nt * 16 + l16;
                float bv = (EPI2 != 0) ? b2[col] : 0.0f;
                #pragma unroll
                for (int r = 0; r < 4; r++) {
                    int row = rbase + mt * 16 + q * 4 + r;
                    if (row < nrows) {
                        float z = acc2[mt][nt][r];
                        if constexpr (EPI2 == 1) z = leaky(z + bv) + e2[(size_t)row * M2 + col];
                        else if constexpr (EPI2 == 2) z = leaky(z + bv + e2[(size_t)row * M2 + col]);
                        if constexpr (sizeof(Out2T) == 2) o2[(size_t)row * M2 + col] = tobf(z);
                        else                              o2[(size_t)row * M2 + col] = z;
                    }
                }
            }
        }
    }
}

// ---------------- gather + leaky: h[d,:] = leaky(sum over in-edges of xw[src,:]) ----
// uint4 loads (16 B/lane = 8 bf16 cols/thread), 2-deep unroll for load ILP.
template<int D>
__global__ __launch_bounds__(256) void gather_kernel(const bf16* __restrict__ xw,
                                                     const int* __restrict__ cnt,
                                                     const int* __restrict__ bucket,
                                                     bf16* __restrict__ h) {
    constexpr int TPN = D / 8;          // threads per node
    constexpr int GP = 256 / TPN;       // nodes per block
    __shared__ int srcs[GP][CAP + 1];   // +1: spread broadcast reads across banks
    int g = threadIdx.x / TPN;
    int c = threadIdx.x % TPN;          // uint4 (8-col) index
    int node = blockIdx.x * GP + g;
    int deg = min(cnt[node], CAP);
    for (int i = c; i < deg; i += TPN) srcs[g][i] = bucket[node * CAP + i];
    __syncthreads();
    const uint4* x4 = (const uint4*)xw;
    float s0 = 0, s1 = 0, s2 = 0, s3 = 0, s4 = 0, s5 = 0, s6 = 0, s7 = 0;
    int i = 0;
    for (; i + 2 <= deg; i += 2) {
        uint4 va = x4[(size_t)srcs[g][i] * (D / 8) + c];
        uint4 vb = x4[(size_t)srcs[g][i + 1] * (D / 8) + c];
        s0 += b2f_lo(va.x); s1 += b2f_hi(va.x);
        s2 += b2f_lo(va.y); s3 += b2f_hi(va.y);
        s4 += b2f_lo(va.z); s5 += b2f_hi(va.z);
        s6 += b2f_lo(va.w); s7 += b2f_hi(va.w);
        s0 += b2f_lo(vb.x); s1 += b2f_hi(vb.x);
        s2 += b2f_lo(vb.y); s3 += b2f_hi(vb.y);
        s4 += b2f_lo(vb.z); s5 += b2f_hi(vb.z);
        s6 += b2f_lo(vb.w); s7 += b2f_hi(vb.w);
    }
    if (i < deg) {
        uint4 va = x4[(size_t)srcs[g][i] * (D / 8) + c];
        s0 += b2f_lo(va.x); s1 += b2f_hi(va.x);
        s2 += b2f_lo(va.y); s3 += b2f_hi(va.y);
        s4 += b2f_lo(va.z); s5 += b2f_hi(va.z);
        s6 += b2f_lo(va.w); s7 += b2f_hi(va.w);
    }
    uint4 o;
    o.x = pk2(leaky(s0), leaky(s1));
    o.y = pk2(leaky(s2), leaky(s3));
    o.z = pk2(leaky(s4), leaky(s5));
    o.w = pk2(leaky(s6), leaky(s7));
    *(uint4*)(h + (size_t)node * D + c * 8) = o;
}

extern "C" void kernel_launch(void* const* d_in, const int* in_sizes, int n_in,
                              void* d_out, int out_size, void* d_ws, size_t ws_size,
                              hipStream_t stream) {
    // Robust input mapping by element count (canonical setup_inputs order as fallback).
    const void* p[16];
    for (int i = 0; i < 16 && i < n_in; i++) p[i] = d_in[i];
    if (n_in == 16) {
        int n8192 = 0, n4096 = 0, n64 = 0;
        const int idx64[4] = {7, 9, 12, 14};
        const int idx4096[3] = {10, 11, 13};
        for (int i = 0; i < 16; i++) {
            switch (in_sizes[i]) {
                case 61440000: p[0] = d_in[i]; break;                  // features
                case 6400000:  p[1] = d_in[i]; break;                  // id_embedding
                case 5120000:  p[2] = d_in[i]; break;                  // preference
                case 131072:   p[3] = d_in[i]; break;                  // mlp_w
                case 128:      p[4] = d_in[i]; break;                  // mlp_b
                case 16384:    p[5] = d_in[i]; break;                  // conv1_w
                case 8192:     p[n8192++ ? 8 : 6] = d_in[i]; break;    // lin1_w, g1_w
                case 64:       if (n64 < 4) p[idx64[n64++]] = d_in[i]; break;
                case 4096:     if (n4096 < 3) p[idx4096[n4096++]] = d_in[i]; break;
                case 3200000:  p[15] = d_in[i]; break;                 // edge_index
                default: break;
            }
        }
    }
    const float* features = (const float*)p[0];
    const float* id_emb   = (const float*)p[1];
    const float* pref     = (const float*)p[2];
    const float* mlp_w    = (const float*)p[3];
    const float* mlp_b    = (const float*)p[4];
    const float* conv1_w  = (const float*)p[5];
    const float* lin1_w   = (const float*)p[6];
    const float* lin1_b   = (const float*)p[7];
    const float* g1_w     = (const float*)p[8];
    const float* g1_b     = (const float*)p[9];
    const float* conv2_w  = (const float*)p[10];
    const float* lin2_w   = (const float*)p[11];
    const float* lin2_b   = (const float*)p[12];
    const float* g2_w     = (const float*)p[13];
    const float* g2_b     = (const float*)p[14];
    const int*   ei       = (const int*)p[15];

    char* wsp = (char*)d_ws;
    size_t off = 0;
    auto alloc = [&](size_t bytes) {
        void* ptr = wsp + off;
        off += (bytes + 255) & ~(size_t)255;
        return ptr;
    };
    // regions (sequential lifetimes), ~129 MB total (ws is ~983 MB per fill size):
    //   A: temp[NI,128]bf16 -> h1[NN,128]bf16 -> h2[NN,64]bf16
    //   B: x0[NN,128]bf16   -> xw2[NN,64]bf16
    //   C: mwb[128,1024]bf16 (gemm1 only) -> xw1[NN,128]bf16
    //   D: xhat[NN,64]f32 (layer1) -> xhat2[NN,64]f32 (layer2)
    //   x1[NN,64]bf16 lives in d_out's first half (dead before final f32 write)
    void* regA = alloc((size_t)NN * DL * 2);
    void* regB = alloc((size_t)NN * DL * 2);
    void* regC = alloc((size_t)NN * DL * 2);
    void* regD = alloc((size_t)NN * DI * 4);
    int*  cnt    = (int*) alloc((size_t)NN * 4);
    int*  bucket = (int*) alloc((size_t)NN * CAP * 4);
    bf16* c1t    = (bf16*)alloc((size_t)DL * DL * 2);
    bf16* c2t    = (bf16*)alloc((size_t)DI * DI * 2);
    bf16* l1b    = (bf16*)alloc((size_t)DI * DL * 2);
    bf16* g1b    = (bf16*)alloc((size_t)DI * DL * 2);
    bf16* l2b    = (bf16*)alloc((size_t)DI * DI * 2);
    bf16* g2b    = (bf16*)alloc((size_t)DI * DI * 2);

    bf16*  temp  = (bf16*)regA;
    bf16*  h1    = (bf16*)regA;
    bf16*  h2    = (bf16*)regA;
    bf16*  x0    = (bf16*)regB;
    bf16*  xw2   = (bf16*)regB;
    bf16*  mwb   = (bf16*)regC;       // mlp_w bf16 copy, dead after gemm1
    bf16*  xw1   = (bf16*)regC;
    float* xhat  = (float*)regD;      // layer1 xhat, then layer2 xhat (sequential)
    bf16*  x1    = (bf16*)d_out;      // scratch in output buffer (f32-sized)
    float* out   = (float*)d_out;     // final output: float32

    hipMemsetAsync(cnt, 0, (size_t)NN * 4, stream);
    csr_fill<<<NE / 256, 256, 0, stream>>>(ei, cnt, bucket);
    prep_kernel<<<304, 256, 0, stream>>>(mlp_w, conv1_w, conv2_w, lin1_w, g1_w,
                                         lin2_w, g2_w, mwb, c1t, c2t, l1b, g1b, l2b, g2b);

    gemm1_kernel<<<(NI + 63) / 64, 256, 0, stream>>>(features, mwb, mlp_b, temp);
    norm_kernel<<<NN / 2, 256, 0, stream>>>(pref, temp, x0);

    const int SG = (NN + 127) / 128;
    // ----- layer 1 -----
    // fused: xw1 = x0@c1t ; xhat = leaky(x0@lin1^T + b) + id_emb   (one x0 read)
    fgemm_kernel<DL, DL, 0, bf16, DI, 1, float><<<SG, 256, 0, stream>>>(
        x0, c1t, nullptr, nullptr, xw1, l1b, lin1_b, id_emb, xhat, NN);
    gather_kernel<DL><<<NN / 16, 256, 0, stream>>>(xw1, cnt, bucket, h1);
    // x1 = leaky(h1@g1^T + b + xhat)
    fgemm_kernel<DL, DI, 2, bf16, 0, 0, bf16><<<SG, 256, 0, stream>>>(
        h1, g1b, g1_b, xhat, x1, nullptr, nullptr, nullptr, nullptr, NN);
    // ----- layer 2 -----
    // fused: xw2 = x1@c2t ; xhat2 = leaky(x1@lin2^T + b) + id_emb  (one x1 read)
    fgemm_kernel<DI, DI, 0, bf16, DI, 1, float><<<SG, 256, 0, stream>>>(
        x1, c2t, nullptr, nullptr, xw2, l2b, lin2_b, id_emb, xhat, NN);
    gather_kernel<DI><<<NN / 32, 256, 0, stream>>>(xw2, cnt, bucket, h2);
    // out = leaky(h2@g2^T + b + xhat2)
    fgemm_kernel<DI, DI, 2, float, 0, 0, float><<<SG, 256, 0, stream>>>(
        h2, g2b, g2_b, xhat, out, nullptr, nullptr, nullptr, nullptr, NN);
}